// Round 9
// baseline (39.936 us; speedup 1.0000x reference)
//
#include <hip/hip_runtime.h>

// GD_lagrange_multi fused kernel for MI355X (gfx950).  Round 9: 4-wave
// (256-thread) restructure of the R7 single-barrier pipelined schedule.
// Shapes: W=4, B=32, S=16, G=1024. One block per (w,b): 4 waves, wave owns
// 256 g-rows = 16 MFMA tiles (16x16x16 f16, f32 accum). 1 wave/SIMD ->
// per-SIMD issue work halves vs R7; DS reduce ops/CU/iter 72 -> 20.
//
// Lane layout (per tile), lane l = 16q + m:
//   Om[t]  r = Omega[g0+16t+4q+r][j=m]   (C/D layout, f32 master)
//   OmB[t] e = Omega[g0+16t+4q+e][j=m]   (B-frag, k=g)
//   YpB[t] e = Yp[i=m][g0+16t+4q+e]      (A-frag, k=g)
//   YpA[t] e = Yp[s=4q+e][g0+16t+m]      (A-frag, k=s)
//   lamN_B e = (-mu*lam)[s=4q+e][j=m]    (B-frag, k=s)
// Updates as fused MFMAs:
//   Om_{i+1} = mfma(YpA, lamN_B, C=OmPre_i)            (grad step)
//   OmPre    = mfma(uI_A, OmB, C=Om), u=-mu*rsq(n2)    (norm fold, diag(u))
// Norm n2 via 2 MFMAs: d1 = mfma(sq_A, I_B) (transpose), n2 = mfma(ones_A,
// t1_B) -> n2[g=m] replicated per lane -> 1 rsq/tile.
// Cross-wave lam reduce: mfma(YpB,OmB) partials, write==read pattern,
// lane-contiguous b128 slots, double-buffered, single barrier/iter.
// Schedule per iter i: HOT(Om_{i+1}, P-write) ; gsum from part(P(Om_i)) ->
// lamN_{i+1} ; barrier ; read part(P(Om_{i+1})) ; SHADOW norm-fold.
// Reference semantics: lam step uses OLD Omega, Omega step uses OLD lam.

typedef float    f32x4 __attribute__((ext_vector_type(4)));
typedef _Float16 f16x4 __attribute__((ext_vector_type(4)));
typedef __fp16   h16x2 __attribute__((ext_vector_type(2)));

#define MUv 1e-3f
#define ROv 1e-3f

__device__ __forceinline__ f16x4 pack4(float a, float b, float c, float d) {
  h16x2 lo = __builtin_amdgcn_cvt_pkrtz(a, b);
  h16x2 hi = __builtin_amdgcn_cvt_pkrtz(c, d);
  union { struct { h16x2 lo, hi; } p; f16x4 v; } u;
  u.p.lo = lo; u.p.hi = hi;
  return u.v;
}

__device__ __forceinline__ f16x4 pack_dup(float a) {
  h16x2 d = __builtin_amdgcn_cvt_pkrtz(a, a);
  union { struct { h16x2 lo, hi; } p; f16x4 v; } u;
  u.p.lo = d; u.p.hi = d;
  return u.v;
}

__global__ __launch_bounds__(256, 1) void gd_lagrange_kernel(
    const float* __restrict__ Yp,   // [128][16][1024]
    const float* __restrict__ Uk,   // [128][16][16]
    const float* __restrict__ Lm,   // [128][16][16]
    const float* __restrict__ Om0,  // [128][1024][16]
    const int* __restrict__ nitp,   // [1]
    float* __restrict__ out) {      // [128][1024][16]
  constexpr int S = 16, G = 1024;
  constexpr int YP_LD = 1028;
  constexpr int NT = 16;            // tiles per wave

  const int wb   = blockIdx.x;
  const int tid  = threadIdx.x;
  const int wv   = tid >> 6;        // wave 0..3
  const int lane = tid & 63;
  const int q    = (tid >> 4) & 3;
  const int m    = tid & 15;
  const int g0   = wv * 256;        // wave's g range (256 rows)

  __shared__ float ldsYp[S * YP_LD];   // dead after prologue
  __shared__ float ldsRed[2][4][256];  // per-wave partials, lane-contig b128
  __shared__ float ldsUk[256];
  __shared__ float ldsLm[256];

  const float* ypg = Yp + (size_t)wb * (S * G);
  const float* omg = Om0 + (size_t)wb * (G * S);

  // ---- Om master loads FIRST (HBM latency overlaps Yp staging) ----
  f32x4 Om[NT];
  #pragma unroll
  for (int t = 0; t < NT; ++t)
    #pragma unroll
    for (int r = 0; r < 4; ++r)
      Om[t][r] = omg[(g0 + 16 * t + 4 * q + r) * S + m];

  // ---- stage Yp slice (4096 float4 / 256 threads = 16 rounds) ----
  #pragma unroll
  for (int k = 0; k < 16; ++k) {
    int vi  = k * 256 + tid;
    f32x4 v = ((const f32x4*)ypg)[vi];
    int row = vi >> 8;
    int col = (vi & 255) * 4;
    *(f32x4*)&ldsYp[row * YP_LD + col] = v;
  }
  ldsUk[tid] = Uk[wb * 256 + tid];
  ldsLm[tid] = Lm[wb * 256 + tid];
  __syncthreads();

  // ---- static frags ----
  f16x4 Ifrag, ones1;
  #pragma unroll
  for (int e = 0; e < 4; ++e) {
    Ifrag[e] = (4 * q + e == m) ? (_Float16)1.0f : (_Float16)0.0f;
    ones1[e] = (_Float16)1.0f;
  }

  f16x4 YpA[NT], YpB[NT];
  #pragma unroll
  for (int t = 0; t < NT; ++t) {
    int gt = g0 + 16 * t;
    // row-contiguous: single b128 read + pack
    f32x4 rb = *(const f32x4*)&ldsYp[m * YP_LD + gt + 4 * q];
    YpB[t] = pack4(rb[0], rb[1], rb[2], rb[3]);
    YpA[t] = pack4(ldsYp[(4 * q + 0) * YP_LD + gt + m],
                   ldsYp[(4 * q + 1) * YP_LD + gt + m],
                   ldsYp[(4 * q + 2) * YP_LD + gt + m],
                   ldsYp[(4 * q + 3) * YP_LD + gt + m]);
  }

  // ---- tgt = Uk@Lambda via one MFMA (master layout D[4q+r][m]) ----
  f32x4 tgt;
  {
    f16x4 UkA = pack4(ldsUk[m * 16 + 4 * q + 0], ldsUk[m * 16 + 4 * q + 1],
                      ldsUk[m * 16 + 4 * q + 2], ldsUk[m * 16 + 4 * q + 3]);
    f16x4 LmB = pack4(ldsLm[(4 * q + 0) * 16 + m], ldsLm[(4 * q + 1) * 16 + m],
                      ldsLm[(4 * q + 2) * 16 + m], ldsLm[(4 * q + 3) * 16 + m]);
    f32x4 z = {0.f, 0.f, 0.f, 0.f};
    tgt = __builtin_amdgcn_mfma_f32_16x16x16f16(UkA, LmB, z, 0, 0, 0);
  }

  const int niter = nitp[0];
  const int rslot = lane * 4;
  constexpr float KLAM = -(MUv) * (ROv);   // lamN = -mu*lam master

  // norm-fold: OmPre = Om + u*Om, u = -mu*rsq(n2_row); 3 MFMAs + 1 rsq
  auto norm_fold = [&](const f16x4& omb, const f32x4& om) -> f32x4 {
    f32x4 z = {0.f, 0.f, 0.f, 0.f};
    f16x4 sq = omb * omb;
    f32x4 d1 = __builtin_amdgcn_mfma_f32_16x16x16f16(sq, Ifrag, z, 0, 0, 0);
    f16x4 t1 = pack4(d1[0], d1[1], d1[2], d1[3]);
    f32x4 n2 = __builtin_amdgcn_mfma_f32_16x16x16f16(ones1, t1, z, 0, 0, 0);
    float u  = -MUv * __builtin_amdgcn_rsqf(n2[0]);
    f16x4 uI = Ifrag * pack_dup(u);
    return __builtin_amdgcn_mfma_f32_16x16x16f16(uI, omb, om, 0, 0, 0);
  };

  // ---- prologue: P(Om_0) partials; OmPre_0 ----
  f16x4 OmB[NT];
  #pragma unroll
  for (int t = 0; t < NT; ++t)
    OmB[t] = pack4(Om[t][0], Om[t][1], Om[t][2], Om[t][3]);
  {
    f32x4 a[4];
    #pragma unroll
    for (int c = 0; c < 4; ++c) a[c] = (f32x4){0.f, 0.f, 0.f, 0.f};
    #pragma unroll
    for (int t = 0; t < NT; ++t)
      a[t & 3] = __builtin_amdgcn_mfma_f32_16x16x16f16(YpB[t], OmB[t], a[t & 3], 0, 0, 0);
    *(f32x4*)&ldsRed[0][wv][rslot] = (a[0] + a[1]) + (a[2] + a[3]);
  }
  f32x4 OmPre[NT];
  #pragma unroll
  for (int t = 0; t < NT; ++t)
    OmPre[t] = norm_fold(OmB[t], Om[t]);
  __syncthreads();
  f32x4 part[4];
  #pragma unroll
  for (int w2 = 0; w2 < 4; ++w2)
    part[w2] = *(const f32x4*)&ldsRed[0][w2][rslot];

  f32x4 lamN32 = {0.f, 0.f, 0.f, 0.f};
  f16x4 lamNB  = pack_dup(0.f);     // lamN_0 = 0

  int wbuf = 1;
  for (int it = 0; it < niter; ++it) {
    // ===== HOT: Om_{i+1} = OmPre_i + YpT@lamN_i (fused C); phase B =====
    f32x4 a[4];
    #pragma unroll
    for (int c = 0; c < 4; ++c) a[c] = (f32x4){0.f, 0.f, 0.f, 0.f};
    #pragma unroll
    for (int t = 0; t < NT; ++t) {
      Om[t]  = __builtin_amdgcn_mfma_f32_16x16x16f16(YpA[t], lamNB, OmPre[t], 0, 0, 0);
      OmB[t] = pack4(Om[t][0], Om[t][1], Om[t][2], Om[t][3]);
      a[t & 3] = __builtin_amdgcn_mfma_f32_16x16x16f16(YpB[t], OmB[t], a[t & 3], 0, 0, 0);
    }
    *(f32x4*)&ldsRed[wbuf][wv][rslot] = (a[0] + a[1]) + (a[2] + a[3]);

    // lamN_{i+1} from part = P(Om_i) (read last round; long complete)
    f32x4 gsum  = (part[0] + part[1]) + (part[2] + part[3]);
    f32x4 delta = gsum - tgt;
    #pragma unroll
    for (int e = 0; e < 4; ++e)
      lamN32[e] = fmaf(KLAM, delta[e], lamN32[e]);
    lamNB = pack4(lamN32[0], lamN32[1], lamN32[2], lamN32[3]);

    __syncthreads();

    // read P(Om_{i+1}) partials (consumed next iter)
    #pragma unroll
    for (int w2 = 0; w2 < 4; ++w2)
      part[w2] = *(const f32x4*)&ldsRed[wbuf][w2][rslot];

    // ===== SHADOW: OmPre_{i+1} via MFMA norm-fold =====
    #pragma unroll
    for (int t = 0; t < NT; ++t)
      OmPre[t] = norm_fold(OmB[t], Om[t]);

    wbuf ^= 1;
  }

  // ---- store Omega ----
  float* og = out + (size_t)wb * (G * S);
  #pragma unroll
  for (int t = 0; t < NT; ++t)
    #pragma unroll
    for (int r = 0; r < 4; ++r)
      og[(g0 + 16 * t + 4 * q + r) * S + m] = Om[t][r];
}

extern "C" void kernel_launch(void* const* d_in, const int* in_sizes, int n_in,
                              void* d_out, int out_size, void* d_ws, size_t ws_size,
                              hipStream_t stream) {
  const float* Yp  = (const float*)d_in[0];
  const float* Uk  = (const float*)d_in[1];
  const float* Lm  = (const float*)d_in[2];
  const float* Om0 = (const float*)d_in[3];
  const int*   nit = (const int*)d_in[4];
  float* out = (float*)d_out;

  gd_lagrange_kernel<<<dim3(128), dim3(256), 0, stream>>>(Yp, Uk, Lm, Om0, nit, out);
}

// Round 10
// 29.953 us; speedup vs baseline: 1.3333x; 1.3333x over previous
//
#include <hip/hip_runtime.h>

// GD_lagrange_multi fused kernel for MI355X (gfx950).  Round 10:
// R7 core (best, 30.8us) + wv0-only lam-reduce (no extra barrier) +
// coalesced prologue/epilogue + exact diagonal-Lambda target.
// Shapes: W=4, B=32, S=16, G=1024. One block per (w,b): 8 waves (2/SIMD,
// required for latency hiding -- R9's 4-wave config regressed), wave owns
// 128 g-rows = 8 MFMA tiles (16x16x16 f16, f32 accum).
//
// Lane layout (per tile), lane l = 16q + m:
//   Om[t]  r = Omega[g0+16t+4q+r][j=m]   (C/D layout, f32 master)
//   OmB[t] e = Omega[g0+16t+4q+e][j=m]   (B-frag, k=g)
//   YpB[t] e = Yp[i=m][g0+16t+4q+e]      (A-frag, k=g)
//   YpA[t] e = Yp[s=4q+e][g0+16t+m]      (A-frag, k=s)
//   lamN_B e = (-mu*lam)[s=4q+e][j=m]    (B-frag, k=s)
// Fused-MFMA updates:  Om_{i+1} = mfma(YpA, lamN_i, C=OmPre_i);
//   OmPre = mfma(uI, OmB, C=Om), u = -mu*rsq(n2) (norm fold; n2 via 2 MFMAs,
//   1 rsq/tile).  Phase B partial P = Yp@Om: write==read pattern ->
//   lane-contiguous b128 slots, double-buffered.
// Schedule per iter (1 barrier): HOT(Om_{i+1}, P-write; wv0: gsum(P(Om_i)) ->
// lamN_{i+1} -> ldsLam[it&1]) ; barrier ; wv0 reads P(Om_{i+1}) partials,
// others read lamN_{i+1} (b64) ; SHADOW norm-fold.  All LDS slots are
// written pre-barrier / read post-barrier with parity alternation ->
// race-free (reads drain before the next barrier).
// Reference semantics: lam step uses OLD Omega, Omega step uses OLD lam.
// Lambda_k is diagonal by construction (eye*Lk) -> tgt = Uk[s][m]*L[m] exact.

typedef float    f32x4 __attribute__((ext_vector_type(4)));
typedef float    f32x2 __attribute__((ext_vector_type(2)));
typedef _Float16 f16x4 __attribute__((ext_vector_type(4)));
typedef __fp16   h16x2 __attribute__((ext_vector_type(2)));

#define MUv 1e-3f
#define ROv 1e-3f

__device__ __forceinline__ f16x4 pack4(float a, float b, float c, float d) {
  h16x2 lo = __builtin_amdgcn_cvt_pkrtz(a, b);
  h16x2 hi = __builtin_amdgcn_cvt_pkrtz(c, d);
  union { struct { h16x2 lo, hi; } p; f16x4 v; } u;
  u.p.lo = lo; u.p.hi = hi;
  return u.v;
}

__device__ __forceinline__ f16x4 pack_dup(float a) {
  h16x2 d = __builtin_amdgcn_cvt_pkrtz(a, a);
  union { struct { h16x2 lo, hi; } p; f16x4 v; } u;
  u.p.lo = d; u.p.hi = d;
  return u.v;
}

__device__ __forceinline__ f32x2 h4_to_f2(f16x4 h) {
  union { f16x4 h; f32x2 f; } u; u.h = h; return u.f;
}
__device__ __forceinline__ f16x4 f2_to_h4(f32x2 f) {
  union { f16x4 h; f32x2 f; } u; u.f = f; return u.h;
}

__global__ __launch_bounds__(512) void gd_lagrange_kernel(
    const float* __restrict__ Yp,   // [128][16][1024]
    const float* __restrict__ Uk,   // [128][16][16]
    const float* __restrict__ Lm,   // [128][16][16]
    const float* __restrict__ Om0,  // [128][1024][16]
    const int* __restrict__ nitp,   // [1]
    float* __restrict__ out) {      // [128][1024][16]
  constexpr int S = 16, G = 1024;
  constexpr int YP_LD = 1028;

  const int wb   = blockIdx.x;
  const int tid  = threadIdx.x;
  const int wv   = tid >> 6;
  const int lane = tid & 63;
  const int q    = (tid >> 4) & 3;
  const int m    = tid & 15;
  const int g0   = wv * 128;

  __shared__ float ldsYp[S * YP_LD];   // 65792 B (dead after prologue)
  __shared__ float ldsOm[G * S];       // 65536 B (prologue stage + epilogue)
  __shared__ float ldsRed[2][8][256];  // 16384 B partials, lane-contig b128
  __shared__ float ldsLam[2][128];     // 1 KB lamN broadcast (b64/lane)

  const float* ypg = Yp + (size_t)wb * (S * G);
  const float* omg = Om0 + (size_t)wb * (G * S);

  // ---- coalesced stage: Om (linear) + Yp (padded rows), 8 rounds ----
  #pragma unroll
  for (int k = 0; k < 8; ++k) {
    int vi = k * 512 + tid;
    *(f32x4*)&ldsOm[vi * 4] = ((const f32x4*)omg)[vi];
    f32x4 v = ((const f32x4*)ypg)[vi];
    int row = vi >> 8;
    int col = (vi & 255) * 4;
    *(f32x4*)&ldsYp[row * YP_LD + col] = v;
  }

  // ---- tgt (wv0 only): (Uk@Lambda)[4q+e][m] = Uk[4q+e][m]*Ldiag[m], exact ----
  f32x4 tgt = {0.f, 0.f, 0.f, 0.f};
  if (wv == 0) {
    const float* uk = Uk + wb * 256;
    const float* lm = Lm + wb * 256;
    float Ld = lm[m * 16 + m];
    #pragma unroll
    for (int e = 0; e < 4; ++e)
      tgt[e] = uk[(4 * q + e) * 16 + m] * Ld;
  }
  __syncthreads();

  // ---- static frags ----
  f16x4 Ifrag, ones1;
  #pragma unroll
  for (int e = 0; e < 4; ++e) {
    Ifrag[e] = (4 * q + e == m) ? (_Float16)1.0f : (_Float16)0.0f;
    ones1[e] = (_Float16)1.0f;
  }

  f16x4 YpA[8], YpB[8];
  #pragma unroll
  for (int t = 0; t < 8; ++t) {
    int gt = g0 + 16 * t;
    f32x4 rb = *(const f32x4*)&ldsYp[m * YP_LD + gt + 4 * q];   // one b128
    YpB[t] = pack4(rb[0], rb[1], rb[2], rb[3]);
    YpA[t] = pack4(ldsYp[(4 * q + 0) * YP_LD + gt + m],
                   ldsYp[(4 * q + 1) * YP_LD + gt + m],
                   ldsYp[(4 * q + 2) * YP_LD + gt + m],
                   ldsYp[(4 * q + 3) * YP_LD + gt + m]);
  }

  // ---- Om master from ldsOm ----
  f32x4 Om[8];
  #pragma unroll
  for (int t = 0; t < 8; ++t)
    #pragma unroll
    for (int r = 0; r < 4; ++r)
      Om[t][r] = ldsOm[(g0 + 16 * t + 4 * q + r) * S + m];

  const int niter = nitp[0];
  const int rslot = lane * 4;
  constexpr float KLAM = -(MUv) * (ROv);   // lamN = -mu*lam master

  // norm-fold: OmPre = Om + u*Om, u = -mu*rsq(n2_row); 3 MFMAs + 1 rsq
  auto norm_fold = [&](const f16x4& omb, const f32x4& om) -> f32x4 {
    f32x4 z = {0.f, 0.f, 0.f, 0.f};
    f16x4 sq = omb * omb;
    f32x4 d1 = __builtin_amdgcn_mfma_f32_16x16x16f16(sq, Ifrag, z, 0, 0, 0);
    f16x4 t1 = pack4(d1[0], d1[1], d1[2], d1[3]);
    f32x4 n2 = __builtin_amdgcn_mfma_f32_16x16x16f16(ones1, t1, z, 0, 0, 0);
    float u  = -MUv * __builtin_amdgcn_rsqf(n2[0]);
    f16x4 uI = Ifrag * pack_dup(u);
    return __builtin_amdgcn_mfma_f32_16x16x16f16(uI, omb, om, 0, 0, 0);
  };

  // ---- prologue round: P(Om_0) -> slot0; OmPre_0 ----
  f16x4 OmB[8];
  #pragma unroll
  for (int t = 0; t < 8; ++t)
    OmB[t] = pack4(Om[t][0], Om[t][1], Om[t][2], Om[t][3]);
  {
    f32x4 a[4];
    #pragma unroll
    for (int c = 0; c < 4; ++c) a[c] = (f32x4){0.f, 0.f, 0.f, 0.f};
    #pragma unroll
    for (int t = 0; t < 8; ++t)
      a[t & 3] = __builtin_amdgcn_mfma_f32_16x16x16f16(YpB[t], OmB[t], a[t & 3], 0, 0, 0);
    *(f32x4*)&ldsRed[0][wv][rslot] = (a[0] + a[1]) + (a[2] + a[3]);
  }
  f32x4 OmPre[8];
  #pragma unroll
  for (int t = 0; t < 8; ++t)
    OmPre[t] = norm_fold(OmB[t], Om[t]);
  __syncthreads();   // b_{-1}

  f32x4 part[8];
  if (wv == 0) {
    #pragma unroll
    for (int w2 = 0; w2 < 8; ++w2)
      part[w2] = *(const f32x4*)&ldsRed[0][w2][rslot];
  }
  f16x4 lam_use = pack_dup(0.f);        // lamN_0 = 0
  f32x4 lamN32  = {0.f, 0.f, 0.f, 0.f}; // wv0 master
  f16x4 lamH    = pack_dup(0.f);        // wv0 reg copy of lamN_{i+1}

  for (int it = 0; it < niter; ++it) {
    const int wn = (it + 1) & 1;

    // ===== HOT: Om_{i+1} = OmPre_i + YpT@lamN_i (fused C); phase B =====
    f32x4 a[4];
    #pragma unroll
    for (int c = 0; c < 4; ++c) a[c] = (f32x4){0.f, 0.f, 0.f, 0.f};
    #pragma unroll
    for (int t = 0; t < 8; ++t) {
      Om[t]  = __builtin_amdgcn_mfma_f32_16x16x16f16(YpA[t], lam_use, OmPre[t], 0, 0, 0);
      OmB[t] = pack4(Om[t][0], Om[t][1], Om[t][2], Om[t][3]);
      a[t & 3] = __builtin_amdgcn_mfma_f32_16x16x16f16(YpB[t], OmB[t], a[t & 3], 0, 0, 0);
    }
    *(f32x4*)&ldsRed[wn][wv][rslot] = (a[0] + a[1]) + (a[2] + a[3]);

    // wv0: lamN_{i+1} from P(Om_i); broadcast packed f16x4 (b64)
    if (wv == 0) {
      f32x4 gsum = ((part[0] + part[1]) + (part[2] + part[3])) +
                   ((part[4] + part[5]) + (part[6] + part[7]));
      f32x4 delta = gsum - tgt;
      #pragma unroll
      for (int e = 0; e < 4; ++e)
        lamN32[e] = fmaf(KLAM, delta[e], lamN32[e]);
      lamH = pack4(lamN32[0], lamN32[1], lamN32[2], lamN32[3]);
      *(f32x2*)&ldsLam[it & 1][lane * 2] = h4_to_f2(lamH);
    }

    __syncthreads();   // b_it

    if (wv == 0) {
      #pragma unroll
      for (int w2 = 0; w2 < 8; ++w2)
        part[w2] = *(const f32x4*)&ldsRed[wn][w2][rslot];
      lam_use = lamH;
    } else {
      lam_use = f2_to_h4(*(const f32x2*)&ldsLam[it & 1][lane * 2]);
    }

    // ===== SHADOW: OmPre_{i+1} via MFMA norm-fold =====
    #pragma unroll
    for (int t = 0; t < 8; ++t)
      OmPre[t] = norm_fold(OmB[t], Om[t]);
  }

  // ---- epilogue: master -> ldsOm -> coalesced float4 stores ----
  __syncthreads();   // ldsOm free (prologue reads long done); order waves
  #pragma unroll
  for (int t = 0; t < 8; ++t)
    #pragma unroll
    for (int r = 0; r < 4; ++r)
      ldsOm[(g0 + 16 * t + 4 * q + r) * S + m] = Om[t][r];
  __syncthreads();
  float* og = out + (size_t)wb * (G * S);
  #pragma unroll
  for (int k = 0; k < 8; ++k) {
    int vi = k * 512 + tid;
    ((f32x4*)og)[vi] = *(const f32x4*)&ldsOm[vi * 4];
  }
}

extern "C" void kernel_launch(void* const* d_in, const int* in_sizes, int n_in,
                              void* d_out, int out_size, void* d_ws, size_t ws_size,
                              hipStream_t stream) {
  const float* Yp  = (const float*)d_in[0];
  const float* Uk  = (const float*)d_in[1];
  const float* Lm  = (const float*)d_in[2];
  const float* Om0 = (const float*)d_in[3];
  const int*   nit = (const int*)d_in[4];
  float* out = (float*)d_out;

  gd_lagrange_kernel<<<dim3(128), dim3(512), 0, stream>>>(Yp, Uk, Lm, Om0, nit, out);
}